// Round 5
// baseline (453.785 us; speedup 1.0000x reference)
//
#include <hip/hip_runtime.h>

#define NODE_DIM 256
#define HIDDEN 64
#define NUM_REL 10

// Per node, all in np/BLAS rounding order (acc=0, ascending-k fmaf chain,
// bias added AFTER accumulation as a separate add):
//   h1 = relu((x @ W1) + b1)
//   h  = (h1 @ W2) + b2              -> stored (edge col-half input)
//   A  = h @ W3[0:64]   (NO bias)    -> stored (fp32 chain prefix for edges)
__global__ __launch_bounds__(256) void node_kernel(
    const float* __restrict__ x,
    const float* __restrict__ W1, const float* __restrict__ b1,
    const float* __restrict__ W2, const float* __restrict__ b2,
    const float* __restrict__ W3,
    float* __restrict__ Hout, float* __restrict__ Aout, int N)
{
    int n = blockIdx.x * 256 + threadIdx.x;
    if (n >= N) return;

    // ---- L1: h1 = relu((x@W1) + b1) ----
    float h1[64];
    #pragma unroll
    for (int j = 0; j < 64; ++j) h1[j] = 0.0f;

    const float4* xr = (const float4*)(x + (size_t)n * NODE_DIM);
    #pragma unroll 1
    for (int k4 = 0; k4 < NODE_DIM / 4; ++k4) {
        float4 xv = xr[k4];
        const float* w = W1 + (size_t)k4 * 4 * 64;
        #pragma unroll
        for (int j = 0; j < 64; ++j) h1[j] = fmaf(xv.x, w[j], h1[j]);
        #pragma unroll
        for (int j = 0; j < 64; ++j) h1[j] = fmaf(xv.y, w[64 + j], h1[j]);
        #pragma unroll
        for (int j = 0; j < 64; ++j) h1[j] = fmaf(xv.z, w[128 + j], h1[j]);
        #pragma unroll
        for (int j = 0; j < 64; ++j) h1[j] = fmaf(xv.w, w[192 + j], h1[j]);
    }
    #pragma unroll
    for (int j = 0; j < 64; ++j) h1[j] = fmaxf(h1[j] + b1[j], 0.0f);

    // ---- L2: h = (h1@W2) + b2 ----
    float h[64];
    #pragma unroll
    for (int c = 0; c < 4; ++c) {
        float acc[16];
        #pragma unroll
        for (int j = 0; j < 16; ++j) acc[j] = 0.0f;
        #pragma unroll
        for (int k = 0; k < 64; ++k) {
            const float* w = W2 + (size_t)k * 64 + c * 16;
            #pragma unroll
            for (int j = 0; j < 16; ++j) acc[j] = fmaf(h1[k], w[j], acc[j]);
        }
        #pragma unroll
        for (int j = 0; j < 16; ++j) h[c * 16 + j] = acc[j] + b2[c * 16 + j];
    }

    float4* hr = (float4*)(Hout + (size_t)n * 64);
    #pragma unroll
    for (int j4 = 0; j4 < 16; ++j4) {
        float4 v;
        v.x = h[4 * j4]; v.y = h[4 * j4 + 1];
        v.z = h[4 * j4 + 2]; v.w = h[4 * j4 + 3];
        hr[j4] = v;
    }

    // ---- L3 row-half partial: A = h @ W3[0:64], no bias ----
    float4* ar = (float4*)(Aout + (size_t)n * 64);
    #pragma unroll
    for (int c = 0; c < 4; ++c) {
        float acc[16];
        #pragma unroll
        for (int j = 0; j < 16; ++j) acc[j] = 0.0f;
        #pragma unroll
        for (int k = 0; k < 64; ++k) {
            const float* w = W3 + (size_t)k * 64 + c * 16;
            #pragma unroll
            for (int j = 0; j < 16; ++j) acc[j] = fmaf(h[k], w[j], acc[j]);
        }
        #pragma unroll
        for (int j4 = 0; j4 < 4; ++j4) {
            float4 v;
            v.x = acc[4 * j4]; v.y = acc[4 * j4 + 1];
            v.z = acc[4 * j4 + 2]; v.w = acc[4 * j4 + 3];
            ar[c * 4 + j4] = v;
        }
    }
}

// Per edge: continue the fp32 chain from A[row] with h[col] over W3 rows
// 64..127 (ascending), + b3, relu; logits chain over W4, + b4; argmax
// (first occurrence), fp32 softmax.
__global__ __launch_bounds__(256) void edge_kernel(
    const int* __restrict__ ei,
    const float* __restrict__ H, const float* __restrict__ A,
    const float* __restrict__ W3, const float* __restrict__ b3,
    const float* __restrict__ W4, const float* __restrict__ b4,
    float* __restrict__ out_type, float* __restrict__ out_probs, int E)
{
    int e = blockIdx.x * 256 + threadIdx.x;
    if (e >= E) return;

    int r = ei[e];
    int c = ei[E + e];

    float hid[64];
    const float4* Ar = (const float4*)(A + (size_t)r * 64);
    #pragma unroll
    for (int j4 = 0; j4 < 16; ++j4) {
        float4 v = Ar[j4];
        hid[4 * j4] = v.x; hid[4 * j4 + 1] = v.y;
        hid[4 * j4 + 2] = v.z; hid[4 * j4 + 3] = v.w;
    }

    float hc[64];
    const float4* Hc = (const float4*)(H + (size_t)c * 64);
    #pragma unroll
    for (int j4 = 0; j4 < 16; ++j4) {
        float4 v = Hc[j4];
        hc[4 * j4] = v.x; hc[4 * j4 + 1] = v.y;
        hc[4 * j4 + 2] = v.z; hc[4 * j4 + 3] = v.w;
    }

    // col-half of the concat-gemm chain: W3 rows 64..127, ascending
    const float* W3b = W3 + 64 * 64;
    #pragma unroll
    for (int k = 0; k < 64; ++k) {
        const float* w = W3b + (size_t)k * 64;
        #pragma unroll
        for (int j = 0; j < 64; ++j) hid[j] = fmaf(hc[k], w[j], hid[j]);
    }
    #pragma unroll
    for (int j = 0; j < 64; ++j) hid[j] = fmaxf(hid[j] + b3[j], 0.0f);

    // logits = (hid @ W4) + b4
    float lg[NUM_REL];
    #pragma unroll
    for (int j = 0; j < NUM_REL; ++j) lg[j] = 0.0f;
    #pragma unroll
    for (int k = 0; k < 64; ++k) {
        const float* w = W4 + (size_t)k * NUM_REL;
        #pragma unroll
        for (int j = 0; j < NUM_REL; ++j) lg[j] = fmaf(hid[k], w[j], lg[j]);
    }
    #pragma unroll
    for (int j = 0; j < NUM_REL; ++j) lg[j] += b4[j];

    // argmax, first occurrence
    int best = 0;
    float bm = lg[0];
    #pragma unroll
    for (int j = 1; j < NUM_REL; ++j)
        if (lg[j] > bm) { bm = lg[j]; best = j; }

    // softmax fp32
    float p[NUM_REL];
    float sum = 0.0f;
    #pragma unroll
    for (int j = 0; j < NUM_REL; ++j) {
        p[j] = expf(lg[j] - bm);
        sum += p[j];
    }
    float inv = 1.0f / sum;

    out_type[e] = (float)best;
    float* op = out_probs + (size_t)e * NUM_REL;
    #pragma unroll
    for (int j = 0; j < NUM_REL; ++j) op[j] = p[j] * inv;
}

extern "C" void kernel_launch(void* const* d_in, const int* in_sizes, int n_in,
                              void* d_out, int out_size, void* d_ws, size_t ws_size,
                              hipStream_t stream)
{
    const float* x  = (const float*)d_in[0];
    const int*   ei = (const int*)d_in[1];
    const float* W1 = (const float*)d_in[2];
    const float* b1 = (const float*)d_in[3];
    const float* W2 = (const float*)d_in[4];
    const float* b2 = (const float*)d_in[5];
    const float* W3 = (const float*)d_in[6];
    const float* b3 = (const float*)d_in[7];
    const float* W4 = (const float*)d_in[8];
    const float* b4 = (const float*)d_in[9];

    int N = in_sizes[0] / NODE_DIM;   // 100000
    int E = in_sizes[1] / 2;          // 1600000

    // ws: H [N*64] f32 | A [N*64] f32   (51.2 MB total)
    float* H = (float*)d_ws;
    float* A = H + (size_t)N * 64;

    int nb = (N + 255) / 256;
    int eb = (E + 255) / 256;

    float* out_type  = (float*)d_out;
    float* out_probs = (float*)d_out + E;

    hipLaunchKernelGGL(node_kernel, dim3(nb), dim3(256), 0, stream,
                       x, W1, b1, W2, b2, W3, H, A, N);
    hipLaunchKernelGGL(edge_kernel, dim3(eb), dim3(256), 0, stream,
                       ei, H, A, W3, b3, W4, b4, out_type, out_probs, E);
}

// Round 6
// 409.761 us; speedup vs baseline: 1.1074x; 1.1074x over previous
//
#include <hip/hip_runtime.h>

#define NODE_DIM 256
#define HIDDEN 64
#define NUM_REL 10

// Per node, np/BLAS rounding order (acc=0, ascending-k fmaf chain, bias added
// AFTER as separate add):
//   h1 = relu((x@W1)+b1); h = (h1@W2)+b2 -> stored; A = h@W3[0:64] -> stored.
// float4 register arrays + static indices keep everything in VGPRs.
__global__ __launch_bounds__(256, 2) void node_kernel(
    const float* __restrict__ x,
    const float* __restrict__ W1, const float* __restrict__ b1,
    const float* __restrict__ W2, const float* __restrict__ b2,
    const float* __restrict__ W3,
    float* __restrict__ Hout, float* __restrict__ Aout, int N)
{
    int n = blockIdx.x * 256 + threadIdx.x;
    if (n >= N) return;

    // ---- L1: h1 = relu((x@W1) + b1) ----
    float4 h1[16];
    #pragma unroll
    for (int j = 0; j < 16; ++j) h1[j] = make_float4(0.f, 0.f, 0.f, 0.f);

    const float4* xr = (const float4*)(x + (size_t)n * NODE_DIM);
    #pragma unroll 1
    for (int k4 = 0; k4 < NODE_DIM / 4; ++k4) {
        float4 xv = xr[k4];
        const float* wb = W1 + (size_t)k4 * 4 * 64;
        #pragma unroll
        for (int i = 0; i < 4; ++i) {
            float xs = (i == 0) ? xv.x : (i == 1) ? xv.y : (i == 2) ? xv.z : xv.w;
            const float* w = wb + i * 64;
            #pragma unroll
            for (int j = 0; j < 16; ++j) {
                h1[j].x = fmaf(xs, w[4 * j + 0], h1[j].x);
                h1[j].y = fmaf(xs, w[4 * j + 1], h1[j].y);
                h1[j].z = fmaf(xs, w[4 * j + 2], h1[j].z);
                h1[j].w = fmaf(xs, w[4 * j + 3], h1[j].w);
            }
        }
    }
    #pragma unroll
    for (int j = 0; j < 16; ++j) {
        h1[j].x = fmaxf(h1[j].x + b1[4 * j + 0], 0.f);
        h1[j].y = fmaxf(h1[j].y + b1[4 * j + 1], 0.f);
        h1[j].z = fmaxf(h1[j].z + b1[4 * j + 2], 0.f);
        h1[j].w = fmaxf(h1[j].w + b1[4 * j + 3], 0.f);
    }

    // ---- L2: h = (h1@W2) + b2 ----
    float4 h[16];
    #pragma unroll
    for (int j = 0; j < 16; ++j) h[j] = make_float4(0.f, 0.f, 0.f, 0.f);
    #pragma unroll
    for (int k4 = 0; k4 < 16; ++k4) {
        #pragma unroll
        for (int i = 0; i < 4; ++i) {
            float s = (i == 0) ? h1[k4].x : (i == 1) ? h1[k4].y
                    : (i == 2) ? h1[k4].z : h1[k4].w;
            const float* w = W2 + (size_t)(k4 * 4 + i) * 64;
            #pragma unroll
            for (int j = 0; j < 16; ++j) {
                h[j].x = fmaf(s, w[4 * j + 0], h[j].x);
                h[j].y = fmaf(s, w[4 * j + 1], h[j].y);
                h[j].z = fmaf(s, w[4 * j + 2], h[j].z);
                h[j].w = fmaf(s, w[4 * j + 3], h[j].w);
            }
        }
    }
    #pragma unroll
    for (int j = 0; j < 16; ++j) {
        h[j].x += b2[4 * j + 0];
        h[j].y += b2[4 * j + 1];
        h[j].z += b2[4 * j + 2];
        h[j].w += b2[4 * j + 3];
    }

    float4* hr = (float4*)(Hout + (size_t)n * 64);
    #pragma unroll
    for (int j = 0; j < 16; ++j) hr[j] = h[j];

    // ---- L3 row-half partial: A = h @ W3[0:64], no bias ----
    float4 a[16];
    #pragma unroll
    for (int j = 0; j < 16; ++j) a[j] = make_float4(0.f, 0.f, 0.f, 0.f);
    #pragma unroll
    for (int k4 = 0; k4 < 16; ++k4) {
        #pragma unroll
        for (int i = 0; i < 4; ++i) {
            float s = (i == 0) ? h[k4].x : (i == 1) ? h[k4].y
                    : (i == 2) ? h[k4].z : h[k4].w;
            const float* w = W3 + (size_t)(k4 * 4 + i) * 64;
            #pragma unroll
            for (int j = 0; j < 16; ++j) {
                a[j].x = fmaf(s, w[4 * j + 0], a[j].x);
                a[j].y = fmaf(s, w[4 * j + 1], a[j].y);
                a[j].z = fmaf(s, w[4 * j + 2], a[j].z);
                a[j].w = fmaf(s, w[4 * j + 3], a[j].w);
            }
        }
    }
    float4* ar = (float4*)(Aout + (size_t)n * 64);
    #pragma unroll
    for (int j = 0; j < 16; ++j) ar[j] = a[j];
}

// Per edge: hid chain continues from A[row] with h[col] over W3 rows 64..127
// ascending (bit-identical to np's concat-gemm chain), +b3, relu, logits +b4,
// first-occurrence argmax, fp32 softmax. Rows held in float4 registers.
__global__ __launch_bounds__(256, 2) void edge_kernel(
    const int* __restrict__ ei,
    const float* __restrict__ H, const float* __restrict__ A,
    const float* __restrict__ W3, const float* __restrict__ b3,
    const float* __restrict__ W4, const float* __restrict__ b4,
    float* __restrict__ out_type, float* __restrict__ out_probs, int E)
{
    int e = blockIdx.x * 256 + threadIdx.x;
    if (e >= E) return;

    int r = ei[e];
    int c = ei[E + e];

    const float4* Ar = (const float4*)(A + (size_t)r * 64);
    const float4* Hc = (const float4*)(H + (size_t)c * 64);

    // issue all 32 row loads up front; keep both rows in VGPRs
    float4 hid[16], hc[16];
    #pragma unroll
    for (int i = 0; i < 16; ++i) hid[i] = Ar[i];
    #pragma unroll
    for (int i = 0; i < 16; ++i) hc[i] = Hc[i];

    // col-half chain: W3 rows 64..127, ascending k
    const float* W3b = W3 + 64 * 64;
    #pragma unroll
    for (int k4 = 0; k4 < 16; ++k4) {
        #pragma unroll
        for (int i = 0; i < 4; ++i) {
            float s = (i == 0) ? hc[k4].x : (i == 1) ? hc[k4].y
                    : (i == 2) ? hc[k4].z : hc[k4].w;
            const float* w = W3b + (size_t)(k4 * 4 + i) * 64;
            #pragma unroll
            for (int j = 0; j < 16; ++j) {
                hid[j].x = fmaf(s, w[4 * j + 0], hid[j].x);
                hid[j].y = fmaf(s, w[4 * j + 1], hid[j].y);
                hid[j].z = fmaf(s, w[4 * j + 2], hid[j].z);
                hid[j].w = fmaf(s, w[4 * j + 3], hid[j].w);
            }
        }
    }
    #pragma unroll
    for (int j = 0; j < 16; ++j) {
        hid[j].x = fmaxf(hid[j].x + b3[4 * j + 0], 0.f);
        hid[j].y = fmaxf(hid[j].y + b3[4 * j + 1], 0.f);
        hid[j].z = fmaxf(hid[j].z + b3[4 * j + 2], 0.f);
        hid[j].w = fmaxf(hid[j].w + b3[4 * j + 3], 0.f);
    }

    // logits = (hid @ W4) + b4, k ascending
    float lg[NUM_REL];
    #pragma unroll
    for (int j = 0; j < NUM_REL; ++j) lg[j] = 0.0f;
    #pragma unroll
    for (int k4 = 0; k4 < 16; ++k4) {
        #pragma unroll
        for (int i = 0; i < 4; ++i) {
            float s = (i == 0) ? hid[k4].x : (i == 1) ? hid[k4].y
                    : (i == 2) ? hid[k4].z : hid[k4].w;
            const float* w = W4 + (size_t)(k4 * 4 + i) * NUM_REL;
            #pragma unroll
            for (int j = 0; j < NUM_REL; ++j) lg[j] = fmaf(s, w[j], lg[j]);
        }
    }
    #pragma unroll
    for (int j = 0; j < NUM_REL; ++j) lg[j] += b4[j];

    // argmax, first occurrence
    int best = 0;
    float bm = lg[0];
    #pragma unroll
    for (int j = 1; j < NUM_REL; ++j)
        if (lg[j] > bm) { bm = lg[j]; best = j; }

    // softmax fp32
    float p[NUM_REL];
    float sum = 0.0f;
    #pragma unroll
    for (int j = 0; j < NUM_REL; ++j) {
        p[j] = expf(lg[j] - bm);
        sum += p[j];
    }
    float inv = 1.0f / sum;

    out_type[e] = (float)best;
    float* op = out_probs + (size_t)e * NUM_REL;
    #pragma unroll
    for (int j = 0; j < NUM_REL; ++j) op[j] = p[j] * inv;
}

extern "C" void kernel_launch(void* const* d_in, const int* in_sizes, int n_in,
                              void* d_out, int out_size, void* d_ws, size_t ws_size,
                              hipStream_t stream)
{
    const float* x  = (const float*)d_in[0];
    const int*   ei = (const int*)d_in[1];
    const float* W1 = (const float*)d_in[2];
    const float* b1 = (const float*)d_in[3];
    const float* W2 = (const float*)d_in[4];
    const float* b2 = (const float*)d_in[5];
    const float* W3 = (const float*)d_in[6];
    const float* b3 = (const float*)d_in[7];
    const float* W4 = (const float*)d_in[8];
    const float* b4 = (const float*)d_in[9];

    int N = in_sizes[0] / NODE_DIM;   // 100000
    int E = in_sizes[1] / 2;          // 1600000

    // ws: H [N*64] f32 | A [N*64] f32   (51.2 MB total)
    float* H = (float*)d_ws;
    float* A = H + (size_t)N * 64;

    int nb = (N + 255) / 256;
    int eb = (E + 255) / 256;

    float* out_type  = (float*)d_out;
    float* out_probs = (float*)d_out + E;

    hipLaunchKernelGGL(node_kernel, dim3(nb), dim3(256), 0, stream,
                       x, W1, b1, W2, b2, W3, H, A, N);
    hipLaunchKernelGGL(edge_kernel, dim3(eb), dim3(256), 0, stream,
                       ei, H, A, W3, b3, W4, b4, out_type, out_probs, E);
}